// Round 6
// baseline (397.804 us; speedup 1.0000x reference)
//
#include <hip/hip_runtime.h>
#include <hip/hip_bf16.h>
#include <cstddef>
#include <cstdint>

constexpr int Bn = 8, Cn = 256, Tn = 8192;
constexpr int NL = 3;          // layers / dilations (1,2,4)
constexpr int Kc = 768;        // K for both fused GEMMs (3*256)
constexpr float SLOPE = 0.1f;

typedef unsigned short u16;
using bf8   = __attribute__((ext_vector_type(8))) short;  // 8 bf16 = 4 VGPRs
using f32x4 = __attribute__((ext_vector_type(4))) float;

__device__ __forceinline__ float lrelu(float v) { return v > 0.f ? v : SLOPE * v; }
__device__ __forceinline__ u16 f2bf(float f) {
    __hip_bfloat16 h = __float2bfloat16(f);
    return *reinterpret_cast<u16*>(&h);
}

// async global->LDS, 16B per lane. LDS dest is wave-uniform base + lane*16:
// must be issued with ALL lanes active; invalid rows redirect the GLOBAL
// pointer to a zero row (per-lane global addresses are fine).
__device__ __forceinline__ void g2l16(const u16* g, u16* l) {
    __builtin_amdgcn_global_load_lds(
        (const __attribute__((address_space(1))) char*)g,
        (__attribute__((address_space(3))) char*)l, 16, 0, 0);
}

// raw barrier for the pipeline: each wave has already drained its own DMA
// (vmcnt) and LDS reads (lgkmcnt) via the preceding asm; sched_barrier(0)
// stops the compiler moving the next phase's memory ops above the barrier.
__device__ __forceinline__ void pipe_barrier() {
    __builtin_amdgcn_s_barrier();
    __builtin_amdgcn_sched_barrier(0);
}

// ---------------------------------------------------------------------------
// Weight prep (once): bf16 Wcat[l][o][s*256+c] from WC/WP/WF,
// bf16 WAp[l][o][tap*256+c] from WA[l][o][c][tap], bSum = bC+bP+bF,
// zero dummy row (ws re-poisoned each launch).
// ---------------------------------------------------------------------------
__global__ __launch_bounds__(256)
void k_wprep(const float* __restrict__ WC, const float* __restrict__ WP,
             const float* __restrict__ WF, const float* __restrict__ WA,
             const float* __restrict__ bC, const float* __restrict__ bP,
             const float* __restrict__ bF,
             u16* __restrict__ Wcat, u16* __restrict__ WAp, float* __restrict__ bSum,
             u16* __restrict__ zrow)
{
    if (blockIdx.x == 0) zrow[threadIdx.x] = 0;
    const int n1 = NL * Cn * Kc;
    for (int i = blockIdx.x * blockDim.x + threadIdx.x; i < n1;
         i += gridDim.x * blockDim.x) {
        int c = i % Cn;
        int s = (i / Cn) % 3;
        int o = (i / (3 * Cn)) % Cn;
        int l = i / (3 * Cn * Cn);
        size_t src = ((size_t)l * Cn + o) * Cn + c;
        float wc = (s == 0) ? WC[src] : (s == 1) ? WP[src] : WF[src];
        Wcat[i] = f2bf(wc);
        WAp[i] = f2bf(WA[src * 3 + s]);
    }
    for (int i = blockIdx.x * blockDim.x + threadIdx.x; i < NL * Cn;
         i += gridDim.x * blockDim.x)
        bSum[i] = bC[i] + bP[i] + bF[i];
}

// ---------------------------------------------------------------------------
// Layer-0 prep: xT[b][t][c] = bf16(lrelu(x[b][c][t]))  (transpose via LDS)
// ---------------------------------------------------------------------------
__global__ __launch_bounds__(256)
void k_prep(const float* __restrict__ x, u16* __restrict__ xT)
{
    __shared__ float s[64][65];
    const int b = blockIdx.z, c0 = blockIdx.y * 64, t0 = blockIdx.x * 64;
    const int tid = threadIdx.x;
    const float* xb = x + ((size_t)b * Cn + c0) * Tn + t0;

    int tt = tid & 63, c4 = tid >> 6;
    for (int cc = c4; cc < 64; cc += 4)
        s[cc][tt] = xb[(size_t)cc * Tn + tt];
    __syncthreads();

    int ccS = tid & 63, t4 = tid >> 6;
    u16* xTb = xT + ((size_t)b * Tn + t0) * Cn + c0;
    for (int t2 = t4; t2 < 64; t2 += 4)
        xTb[(size_t)t2 * Cn + ccS] = f2bf(lrelu(s[ccS][t2]));
}

// ---------------------------------------------------------------------------
// GEMM1 (256x256 tile): zT[b][t][o] = bf16(lrelu(sum_k X[t][k]*W[o][k]+bS[o]))
//   A = X (m=t, 256), B = W (n=o, full 256). 512 threads, 8 waves:
//   wave = (t-half 128) x (o-quarter 64); acc[8][4], 32 MFMA per K-chunk.
//   Staging: ring-3 slots of 32KB (X 256rows x 64B + W 256rows x 64B),
//   depth-2 prefetch, counted vmcnt(4) (0 only on last chunk).
//   Bank-conflict fix (verified R1): source-side chunk XOR + read-side XOR.
//   Grid 32 x 8 = 256 blocks = exactly 1/CU, single round; staged bytes
//   per dispatch HALVED vs 128x128 (no o-half duplication of X).
// ---------------------------------------------------------------------------
constexpr int SLOTU = 16384;   // u16 per slot: X 8192 + W 8192 (32 KB)

__global__ __launch_bounds__(512, 2)
void k_gemm1(const u16* __restrict__ xT, const float* __restrict__ d,
             const u16* __restrict__ Wl, const float* __restrict__ bS,
             float dil, u16* __restrict__ zT, const u16* __restrict__ zrow)
{
    __shared__ u16 smem[3 * SLOTU];   // 96 KB
    __shared__ int sRow[3][256];

    const int tid = threadIdx.x;
    const int b = blockIdx.z;
    const int t0 = blockIdx.x * 256;

    if (tid < 256) {
        int t = t0 + tid;
        float dv = d[(size_t)b * Tn + t] * dil;
        int ip = (int)rintf((float)t - dv);   // round-half-even == jnp.round
        int iF = (int)rintf((float)t + dv);
        sRow[0][tid] = t;
        sRow[1][tid] = (ip >= 0) ? ip : -1;
        sRow[2][tid] = (iF < Tn) ? iF : -1;
    }
    __syncthreads();

    const int srow = tid >> 2;                 // 0..127 (rows srow, srow+128)
    const int schunkL = (tid & 3) * 8;                       // linear LDS slot
    const int schunkG = ((tid & 3) ^ ((tid >> 3) & 3)) * 8;  // swizzled source
    const u16* xTb = xT + (size_t)b * Tn * Cn;

    const u16 *pr0[3], *pr1[3];
    #pragma unroll
    for (int s = 0; s < 3; ++s) {
        int r0 = sRow[s][srow], r1 = sRow[s][srow + 128];
        pr0[s] = (r0 >= 0) ? (xTb + (size_t)r0 * Cn + schunkG) : (zrow + schunkG);
        pr1[s] = (r1 >= 0) ? (xTb + (size_t)r1 * Cn + schunkG) : (zrow + schunkG);
    }
    const u16* wbase = Wl + (size_t)srow * Kc + schunkG;

    const int lane = tid & 63, wv = tid >> 6;
    const int wt = (wv >> 2) * 128;  // t-half (m)
    const int wo = (wv & 3) * 64;    // o-quarter (n)
    const int lr = lane & 15, quad = lane >> 4;
    const int rchunk = (quad ^ ((lr >> 1) & 3)) * 8;   // read-side un-swizzle

    const int ldsS = srow * 32 + schunkL;          // this thread's DMA slot
    const int ldsS2 = (srow + 128) * 32 + schunkL;

    auto dma = [&](int kg, int slot) {
        int seg = kg >> 3, kk = (kg & 7) * 32;
        u16* bx = smem + slot * SLOTU;
        u16* bw = bx + 8192;
        g2l16(wbase + seg * 256 + kk,                    bw + ldsS);
        g2l16(wbase + (size_t)128 * Kc + seg * 256 + kk, bw + ldsS2);
        g2l16(pr0[seg] + kk, bx + ldsS);
        g2l16(pr1[seg] + kk, bx + ldsS2);
    };

    f32x4 acc[8][4] = {};
    dma(0, 0); dma(1, 1);   // prefetch depth 2 (8 loads in flight)

    #pragma unroll
    for (int kg = 0; kg < 24; ++kg) {
        if (kg < 23)
            asm volatile("s_waitcnt vmcnt(4) lgkmcnt(0)" ::: "memory");
        else
            asm volatile("s_waitcnt vmcnt(0) lgkmcnt(0)" ::: "memory");
        pipe_barrier();

        const u16* bX = smem + (kg % 3) * SLOTU;
        const u16* bW = bX + 8192;

        bf8 af[8], bg[4];
        #pragma unroll
        for (int mi = 0; mi < 8; ++mi)
            af[mi] = *(const bf8*)(bX + (wt + mi * 16 + lr) * 32 + rchunk);
        #pragma unroll
        for (int ni = 0; ni < 4; ++ni)
            bg[ni] = *(const bf8*)(bW + (wo + ni * 16 + lr) * 32 + rchunk);

        if (kg + 2 < 24) dma(kg + 2, (kg + 2) % 3);  // refill ring slot

        __builtin_amdgcn_s_setprio(1);
        #pragma unroll
        for (int mi = 0; mi < 8; ++mi)
            #pragma unroll
            for (int ni = 0; ni < 4; ++ni)
                acc[mi][ni] = __builtin_amdgcn_mfma_f32_16x16x32_bf16(
                    af[mi], bg[ni], acc[mi][ni], 0, 0, 0);
        __builtin_amdgcn_s_setprio(0);
    }

    // epilogue: D row = m = t (quad*4+r), col = n = o (lr)
    float bias[4];
    #pragma unroll
    for (int ni = 0; ni < 4; ++ni) bias[ni] = bS[wo + ni * 16 + lr];
    u16* zTb = zT + (size_t)b * Tn * Cn;
    #pragma unroll
    for (int mi = 0; mi < 8; ++mi)
        #pragma unroll
        for (int r = 0; r < 4; ++r) {
            int t = t0 + wt + mi * 16 + quad * 4 + r;
            u16* row = zTb + (size_t)t * Cn + wo;
            #pragma unroll
            for (int ni = 0; ni < 4; ++ni)
                row[ni * 16 + lr] = f2bf(lrelu(acc[mi][ni][r] + bias[ni]));
        }
}

// ---------------------------------------------------------------------------
// GEMM2 (256x256 tile, conv3 + residual + fused next-layer prep):
//   out[b][o][t] = sum_{tap,c} WAp[o][tap*256+c]*zT[t+tap-1][c] + bA[o] + xres
//   A = W (m=o, full 256), B = Z (n=t, 256). Wave = (o-half 128)x(t-qtr 64).
//   Same ring-3 / counted-vmcnt / swizzle staging. D is o-major per lane ->
//   next-layer xT write is a direct packed ushort4 (no LDS strip).
// ---------------------------------------------------------------------------
__global__ __launch_bounds__(512, 2)
void k_gemm2(const u16* __restrict__ zT, const u16* __restrict__ WAl,
             const float* __restrict__ bA, const float* __restrict__ xres,
             float* __restrict__ out, u16* __restrict__ xTn, int writeXT,
             const u16* __restrict__ zrow)
{
    __shared__ u16 smem[3 * SLOTU];   // 96 KB

    const int tid = threadIdx.x;
    const int b = blockIdx.z;
    const int t0 = blockIdx.x * 256;

    const int srow = tid >> 2;
    const int schunkL = (tid & 3) * 8;
    const int schunkG = ((tid & 3) ^ ((tid >> 3) & 3)) * 8;
    const int lane = tid & 63, wv = tid >> 6;
    const int wo = (wv & 1) * 128;   // o-half (m)
    const int wt = (wv >> 1) * 64;   // t-quarter (n)
    const int lr = lane & 15, quad = lane >> 4;
    const int rchunk = (quad ^ ((lr >> 1) & 3)) * 8;

    const u16* zTb = zT + (size_t)b * Tn * Cn;
    const u16 *zr0[3], *zr1[3];
    #pragma unroll
    for (int tap = 0; tap < 3; ++tap) {
        int r0 = t0 + srow + tap - 1;
        int r1 = r0 + 128;
        zr0[tap] = (r0 >= 0 && r0 < Tn) ? (zTb + (size_t)r0 * Cn + schunkG)
                                        : (zrow + schunkG);
        zr1[tap] = (r1 >= 0 && r1 < Tn) ? (zTb + (size_t)r1 * Cn + schunkG)
                                        : (zrow + schunkG);
    }
    const u16* wbase = WAl + (size_t)srow * Kc + schunkG;

    const int ldsS = srow * 32 + schunkL;
    const int ldsS2 = (srow + 128) * 32 + schunkL;

    auto dma = [&](int kg, int slot) {
        int tap = kg >> 3, kk = (kg & 7) * 32;
        u16* bz = smem + slot * SLOTU;
        u16* bw = bz + 8192;
        g2l16(wbase + tap * 256 + kk,                    bw + ldsS);
        g2l16(wbase + (size_t)128 * Kc + tap * 256 + kk, bw + ldsS2);
        g2l16(zr0[tap] + kk, bz + ldsS);
        g2l16(zr1[tap] + kk, bz + ldsS2);
    };

    f32x4 acc[8][4] = {};
    dma(0, 0); dma(1, 1);

    #pragma unroll
    for (int kg = 0; kg < 24; ++kg) {
        if (kg < 23)
            asm volatile("s_waitcnt vmcnt(4) lgkmcnt(0)" ::: "memory");
        else
            asm volatile("s_waitcnt vmcnt(0) lgkmcnt(0)" ::: "memory");
        pipe_barrier();

        const u16* bZ = smem + (kg % 3) * SLOTU;
        const u16* bW = bZ + 8192;

        bf8 af[8], bg[4];
        #pragma unroll
        for (int mi = 0; mi < 8; ++mi)
            af[mi] = *(const bf8*)(bW + (wo + mi * 16 + lr) * 32 + rchunk);
        #pragma unroll
        for (int ni = 0; ni < 4; ++ni)
            bg[ni] = *(const bf8*)(bZ + (wt + ni * 16 + lr) * 32 + rchunk);

        if (kg + 2 < 24) dma(kg + 2, (kg + 2) % 3);

        __builtin_amdgcn_s_setprio(1);
        #pragma unroll
        for (int mi = 0; mi < 8; ++mi)
            #pragma unroll
            for (int ni = 0; ni < 4; ++ni)
                acc[mi][ni] = __builtin_amdgcn_mfma_f32_16x16x32_bf16(
                    af[mi], bg[ni], acc[mi][ni], 0, 0, 0);
        __builtin_amdgcn_s_setprio(0);
    }

    // epilogue: D row = m = o (quad*4+r), col = n = t (lr); o-major per lane
    u16* xTb2 = xTn + (size_t)b * Tn * Cn;
    #pragma unroll
    for (int mi = 0; mi < 8; ++mi) {
        int ob = wo + mi * 16 + quad * 4;
        float4 bb = *(const float4*)(bA + ob);
        #pragma unroll
        for (int ni = 0; ni < 4; ++ni) {
            int t = t0 + wt + ni * 16 + lr;
            ushort4 px;
            #pragma unroll
            for (int r = 0; r < 4; ++r) {
                size_t idx = ((size_t)b * Cn + ob + r) * Tn + t;
                float v = acc[mi][ni][r] + ((const float*)&bb)[r] + xres[idx];
                out[idx] = v;
                ((u16*)&px)[r] = f2bf(lrelu(v));
            }
            if (writeXT)
                *(ushort4*)(xTb2 + (size_t)t * Cn + ob) = px;
        }
    }
}

extern "C" void kernel_launch(void* const* d_in, const int* in_sizes, int n_in,
                              void* d_out, int out_size, void* d_ws, size_t ws_size,
                              hipStream_t stream)
{
    const float* x  = (const float*)d_in[0];
    const float* d  = (const float*)d_in[1];
    const float* WC = (const float*)d_in[2];
    const float* bC = (const float*)d_in[3];
    const float* WP = (const float*)d_in[4];
    const float* bP = (const float*)d_in[5];
    const float* WF = (const float*)d_in[6];
    const float* bF = (const float*)d_in[7];
    const float* WA = (const float*)d_in[8];
    const float* bA = (const float*)d_in[9];
    float* out = (float*)d_out;

    char* ws = (char*)d_ws;
    u16*   xT   = (u16*)(ws);                                   // 32 MiB
    u16*   zT   = (u16*)(ws + (size_t)Bn * Tn * Cn * 2);        // 32 MiB
    u16*   Wcat = (u16*)(ws + (size_t)2 * Bn * Tn * Cn * 2);    // 1.125 MiB
    u16*   WAp  = Wcat + (size_t)NL * Cn * Kc;                  // 1.125 MiB
    float* bSum = (float*)(WAp + (size_t)NL * Cn * Kc);         // 3 KiB
    u16*   zrow = (u16*)(bSum + NL * Cn);                       // 512 B zero row

    k_wprep<<<dim3(1024), dim3(256), 0, stream>>>(WC, WP, WF, WA, bC, bP, bF,
                                                  Wcat, WAp, bSum, zrow);

    dim3 gP(Tn / 64, Cn / 64, Bn);      // prep: 128 x 4 x 8
    dim3 gG(Tn / 256, 1, Bn);           // gemms: 32 t-tiles x 8 batches = 256
    dim3 blk(512);

    k_prep<<<gP, dim3(256), 0, stream>>>(x, xT);   // layer-0 input only

    const float dils[NL] = {1.f, 2.f, 4.f};
    const float* xcur = x;
    for (int i = 0; i < NL; ++i) {
        k_gemm1<<<gG, blk, 0, stream>>>(xT, d,
                                        Wcat + (size_t)i * Cn * Kc,
                                        bSum + (size_t)i * Cn,
                                        dils[i], zT, zrow);
        k_gemm2<<<gG, blk, 0, stream>>>(zT,
                                        WAp + (size_t)i * Cn * Kc,
                                        bA + (size_t)i * Cn,
                                        xcur, out, xT, (i < NL - 1) ? 1 : 0,
                                        zrow);
        xcur = out;   // residual read-then-write same element: in-place safe
    }
}

// Round 7
// 363.977 us; speedup vs baseline: 1.0929x; 1.0929x over previous
//
#include <hip/hip_runtime.h>
#include <hip/hip_bf16.h>
#include <cstddef>
#include <cstdint>

constexpr int Bn = 8, Cn = 256, Tn = 8192;
constexpr int NL = 3;          // layers / dilations (1,2,4)
constexpr int Kc = 768;        // K for both fused GEMMs (3*256)
constexpr float SLOPE = 0.1f;

typedef unsigned short u16;
using bf8   = __attribute__((ext_vector_type(8))) short;  // 8 bf16 = 4 VGPRs
using f32x4 = __attribute__((ext_vector_type(4))) float;

__device__ __forceinline__ float lrelu(float v) { return v > 0.f ? v : SLOPE * v; }
__device__ __forceinline__ u16 f2bf(float f) {
    __hip_bfloat16 h = __float2bfloat16(f);
    return *reinterpret_cast<u16*>(&h);
}

// async global->LDS, 16B per lane. LDS dest is wave-uniform base + lane*16:
// must be issued with ALL lanes active; invalid rows redirect the GLOBAL
// pointer to a zero row (per-lane global addresses are fine).
__device__ __forceinline__ void g2l16(const u16* g, u16* l) {
    __builtin_amdgcn_global_load_lds(
        (const __attribute__((address_space(1))) char*)g,
        (__attribute__((address_space(3))) char*)l, 16, 0, 0);
}

// raw barrier for the pipeline: each wave has already drained its own DMA
// (vmcnt) and LDS reads (lgkmcnt) via the preceding asm; sched_barrier(0)
// stops the compiler moving the next phase's memory ops above the barrier.
__device__ __forceinline__ void pipe_barrier() {
    __builtin_amdgcn_s_barrier();
    __builtin_amdgcn_sched_barrier(0);
}

// ---------------------------------------------------------------------------
// Weight prep (once): bf16 Wcat[l][o][s*256+c] from WC/WP/WF,
// bf16 WAp[l][o][tap*256+c] from WA[l][o][c][tap], bSum = bC+bP+bF,
// zero dummy row (ws re-poisoned each launch).
// ---------------------------------------------------------------------------
__global__ __launch_bounds__(256)
void k_wprep(const float* __restrict__ WC, const float* __restrict__ WP,
             const float* __restrict__ WF, const float* __restrict__ WA,
             const float* __restrict__ bC, const float* __restrict__ bP,
             const float* __restrict__ bF,
             u16* __restrict__ Wcat, u16* __restrict__ WAp, float* __restrict__ bSum,
             u16* __restrict__ zrow)
{
    if (blockIdx.x == 0) zrow[threadIdx.x] = 0;
    const int n1 = NL * Cn * Kc;
    for (int i = blockIdx.x * blockDim.x + threadIdx.x; i < n1;
         i += gridDim.x * blockDim.x) {
        int c = i % Cn;
        int s = (i / Cn) % 3;
        int o = (i / (3 * Cn)) % Cn;
        int l = i / (3 * Cn * Cn);
        size_t src = ((size_t)l * Cn + o) * Cn + c;
        float wc = (s == 0) ? WC[src] : (s == 1) ? WP[src] : WF[src];
        Wcat[i] = f2bf(wc);
        WAp[i] = f2bf(WA[src * 3 + s]);
    }
    for (int i = blockIdx.x * blockDim.x + threadIdx.x; i < NL * Cn;
         i += gridDim.x * blockDim.x)
        bSum[i] = bC[i] + bP[i] + bF[i];
}

// ---------------------------------------------------------------------------
// Layer-0 prep: xT[b][t][c] = bf16(lrelu(x[b][c][t]))  (transpose via LDS)
// ---------------------------------------------------------------------------
__global__ __launch_bounds__(256)
void k_prep(const float* __restrict__ x, u16* __restrict__ xT)
{
    __shared__ float s[64][65];
    const int b = blockIdx.z, c0 = blockIdx.y * 64, t0 = blockIdx.x * 64;
    const int tid = threadIdx.x;
    const float* xb = x + ((size_t)b * Cn + c0) * Tn + t0;

    int tt = tid & 63, c4 = tid >> 6;
    for (int cc = c4; cc < 64; cc += 4)
        s[cc][tt] = xb[(size_t)cc * Tn + tt];
    __syncthreads();

    int ccS = tid & 63, t4 = tid >> 6;
    u16* xTb = xT + ((size_t)b * Tn + t0) * Cn + c0;
    for (int t2 = t4; t2 < 64; t2 += 4)
        xTb[(size_t)t2 * Cn + ccS] = f2bf(lrelu(s[ccS][t2]));
}

// ---------------------------------------------------------------------------
// GEMM1: zT[b][t][o] = bf16(lrelu( sum_k Xcat[t][k]*Wcat[o][k] + bSum[o] ))
//   A = X (m=t), B = W (n=o). 128x128 tile, 4 waves of 64x64.
//   XCD pair-swizzle: fid -> xcd=fid&7 owns 8 consecutive t-tiles x both
//   o-halves, so the o-pair shares X-gather rows in its private L2.
//   K-loop: ring-4 LDS slots, 12 phases of 2 K-chunks each; DMA for the
//   next 2 slots issued right after the barrier; chunk k+1's ds_read
//   latency hidden under chunk k's MFMA via split lgkmcnt(8)/lgkmcnt(0).
//   Bank-conflict fix (verified R1): source-side chunk XOR + read-side XOR.
// ---------------------------------------------------------------------------
__global__ __launch_bounds__(256, 2)
void k_gemm1(const u16* __restrict__ xT, const float* __restrict__ d,
             const u16* __restrict__ Wl, const float* __restrict__ bS,
             float dil, u16* __restrict__ zT, const u16* __restrict__ zrow)
{
    __shared__ u16 smem[8 * 4096];   // X slots 0..3, then W slots 0..3 (8KB each)
    __shared__ int sRow[3][128];

    const int tid = threadIdx.x;
    const int b = blockIdx.z;
    const int fid = blockIdx.x;               // 0..127
    const int j = fid >> 3;
    const int o0 = (j & 1) * 128;
    const int t0 = ((fid & 7) * 8 + (j >> 1)) * 128;

    if (tid < 128) {
        int t = t0 + tid;
        float dv = d[(size_t)b * Tn + t] * dil;
        int ip = (int)rintf((float)t - dv);   // round-half-even == jnp.round
        int iF = (int)rintf((float)t + dv);
        sRow[0][tid] = t;
        sRow[1][tid] = (ip >= 0) ? ip : -1;
        sRow[2][tid] = (iF < Tn) ? iF : -1;
    }
    __syncthreads();

    const int srow = tid >> 2;                 // 0..63 (rows srow, srow+64)
    const int schunkL = (tid & 3) * 8;                       // linear LDS slot
    const int schunkG = ((tid & 3) ^ ((tid >> 3) & 3)) * 8;  // swizzled source
    const u16* xTb = xT + (size_t)b * Tn * Cn;

    const u16 *pr0[3], *pr1[3];
    #pragma unroll
    for (int s = 0; s < 3; ++s) {
        int r0 = sRow[s][srow], r1 = sRow[s][srow + 64];
        pr0[s] = (r0 >= 0) ? (xTb + (size_t)r0 * Cn + schunkG) : (zrow + schunkG);
        pr1[s] = (r1 >= 0) ? (xTb + (size_t)r1 * Cn + schunkG) : (zrow + schunkG);
    }
    const u16* wbase = Wl + (size_t)(o0 + srow) * Kc + schunkG;

    const int lane = tid & 63, wv = tid >> 6;
    const int wm = (wv & 1) * 64;   // t-half
    const int wn = (wv >> 1) * 64;  // o-half
    const int lr = lane & 15, quad = lane >> 4;
    const int rchunk = (quad ^ ((lr >> 1) & 3)) * 8;   // read-side un-swizzle

    const int ldsW = srow * 32 + schunkL;          // this thread's DMA slot
    const int ldsW2 = (srow + 64) * 32 + schunkL;

    auto dma = [&](int kg, int bsel) {
        int seg = kg >> 3, kk = (kg & 7) * 32;
        u16* bx = smem + bsel * 4096;
        u16* bw = smem + 16384 + bsel * 4096;
        g2l16(wbase + seg * 256 + kk,                   bw + ldsW);
        g2l16(wbase + (size_t)64 * Kc + seg * 256 + kk, bw + ldsW2);
        g2l16(pr0[seg] + kk, bx + ldsW);
        g2l16(pr1[seg] + kk, bx + ldsW2);
    };

    f32x4 acc[4][4] = {};
    dma(0, 0); dma(1, 1);

    #pragma unroll
    for (int P = 0; P < 12; ++P) {
        const int k0 = 2 * P, k1 = 2 * P + 1;
        asm volatile("s_waitcnt vmcnt(0) lgkmcnt(0)" ::: "memory");
        pipe_barrier();
        if (P < 11) { dma(k0 + 2, (k0 + 2) & 3); dma(k1 + 2, (k1 + 2) & 3); }
        __builtin_amdgcn_sched_barrier(0);

        const u16* bX0 = smem + (k0 & 3) * 4096;
        const u16* bW0 = smem + 16384 + (k0 & 3) * 4096;
        const u16* bX1 = smem + (k1 & 3) * 4096;
        const u16* bW1 = smem + 16384 + (k1 & 3) * 4096;

        bf8 a0[4], g0[4], a1[4], g1[4];
        #pragma unroll
        for (int mi = 0; mi < 4; ++mi)
            a0[mi] = *(const bf8*)(bX0 + (wm + mi * 16 + lr) * 32 + rchunk);
        #pragma unroll
        for (int ni = 0; ni < 4; ++ni)
            g0[ni] = *(const bf8*)(bW0 + (wn + ni * 16 + lr) * 32 + rchunk);
        __builtin_amdgcn_sched_barrier(0);
        #pragma unroll
        for (int mi = 0; mi < 4; ++mi)
            a1[mi] = *(const bf8*)(bX1 + (wm + mi * 16 + lr) * 32 + rchunk);
        #pragma unroll
        for (int ni = 0; ni < 4; ++ni)
            g1[ni] = *(const bf8*)(bW1 + (wn + ni * 16 + lr) * 32 + rchunk);

        asm volatile("s_waitcnt lgkmcnt(8)" ::: "memory");
        __builtin_amdgcn_sched_barrier(0);
        __builtin_amdgcn_s_setprio(1);
        #pragma unroll
        for (int mi = 0; mi < 4; ++mi)
            #pragma unroll
            for (int ni = 0; ni < 4; ++ni)
                acc[mi][ni] = __builtin_amdgcn_mfma_f32_16x16x32_bf16(
                    a0[mi], g0[ni], acc[mi][ni], 0, 0, 0);
        __builtin_amdgcn_s_setprio(0);

        asm volatile("s_waitcnt lgkmcnt(0)" ::: "memory");
        __builtin_amdgcn_sched_barrier(0);
        __builtin_amdgcn_s_setprio(1);
        #pragma unroll
        for (int mi = 0; mi < 4; ++mi)
            #pragma unroll
            for (int ni = 0; ni < 4; ++ni)
                acc[mi][ni] = __builtin_amdgcn_mfma_f32_16x16x32_bf16(
                    a1[mi], g1[ni], acc[mi][ni], 0, 0, 0);
        __builtin_amdgcn_s_setprio(0);
    }

    // epilogue: D row = m = t (quad*4+r), col = n = o (lr)
    float bias[4];
    #pragma unroll
    for (int ni = 0; ni < 4; ++ni) bias[ni] = bS[o0 + wn + ni * 16 + lr];
    u16* zTb = zT + (size_t)b * Tn * Cn;
    #pragma unroll
    for (int mi = 0; mi < 4; ++mi)
        #pragma unroll
        for (int r = 0; r < 4; ++r) {
            int t = t0 + wm + mi * 16 + quad * 4 + r;
            u16* row = zTb + (size_t)t * Cn + o0 + wn;
            #pragma unroll
            for (int ni = 0; ni < 4; ++ni)
                row[ni * 16 + lr] = f2bf(lrelu(acc[mi][ni][r] + bias[ni]));
        }
}

// ---------------------------------------------------------------------------
// GEMM2 (conv3 + residual + fused next-layer prep):
//   out[b][o][t] = sum_{tap,c} WAp[o][tap*256+c]*zT[t+tap-1][c] + bA[o] + xres
//   if writeXT: xTn[b][t][o] = bf16(lrelu(out))  (per-wave LDS transpose)
//   A = W (m=o), B = Z (n=t). Same 2-kg-phase pipeline + XCD pair swizzle.
//   Epilogue (R7): part A = barrier-free rolling 2-deep xres prefetch over
//   ni-groups (out writes of group ni overlap reads of ni+1; __restrict__
//   permits the read hoist; packed bf16 saved in pkv). Part B = the
//   coalesced LDS-strip xT transpose consuming pkv (writes only).
// ---------------------------------------------------------------------------
__global__ __launch_bounds__(256, 2)
void k_gemm2(const u16* __restrict__ zT, const u16* __restrict__ WAl,
             const float* __restrict__ bA, const float* __restrict__ xres,
             float* __restrict__ out, u16* __restrict__ xTn, int writeXT,
             const u16* __restrict__ zrow)
{
    __shared__ u16 smem[8 * 4096];   // Z slots 0..3, W slots 0..3; epilogue reuses

    const int tid = threadIdx.x;
    const int b = blockIdx.z;
    const int fid = blockIdx.x;               // 0..127
    const int j = fid >> 3;
    const int o0 = (j & 1) * 128;
    const int t0 = ((fid & 7) * 8 + (j >> 1)) * 128;

    const int srow = tid >> 2;
    const int schunkL = (tid & 3) * 8;
    const int schunkG = ((tid & 3) ^ ((tid >> 3) & 3)) * 8;
    const int lane = tid & 63, wv = tid >> 6;
    const int wo = (wv & 1) * 64;   // o-half (m)
    const int wt = (wv >> 1) * 64;  // t-half (n)
    const int lr = lane & 15, quad = lane >> 4;
    const int rchunk = (quad ^ ((lr >> 1) & 3)) * 8;

    const u16* zTb = zT + (size_t)b * Tn * Cn;
    const u16 *zr0[3], *zr1[3];
    #pragma unroll
    for (int tap = 0; tap < 3; ++tap) {
        int r0 = t0 + srow + tap - 1;
        int r1 = r0 + 64;
        zr0[tap] = (r0 >= 0 && r0 < Tn) ? (zTb + (size_t)r0 * Cn + schunkG)
                                        : (zrow + schunkG);
        zr1[tap] = (r1 >= 0 && r1 < Tn) ? (zTb + (size_t)r1 * Cn + schunkG)
                                        : (zrow + schunkG);
    }
    const u16* wbase = WAl + (size_t)(o0 + srow) * Kc + schunkG;

    const int ldsW = srow * 32 + schunkL;
    const int ldsW2 = (srow + 64) * 32 + schunkL;

    auto dma = [&](int kg, int bsel) {
        int tap = kg >> 3, kk = (kg & 7) * 32;
        u16* bz = smem + bsel * 4096;
        u16* bw = smem + 16384 + bsel * 4096;
        g2l16(wbase + tap * 256 + kk,                   bw + ldsW);
        g2l16(wbase + (size_t)64 * Kc + tap * 256 + kk, bw + ldsW2);
        g2l16(zr0[tap] + kk, bz + ldsW);
        g2l16(zr1[tap] + kk, bz + ldsW2);
    };

    f32x4 acc[4][4] = {};
    dma(0, 0); dma(1, 1);

    #pragma unroll
    for (int P = 0; P < 12; ++P) {
        const int k0 = 2 * P, k1 = 2 * P + 1;
        asm volatile("s_waitcnt vmcnt(0) lgkmcnt(0)" ::: "memory");
        pipe_barrier();
        if (P < 11) { dma(k0 + 2, (k0 + 2) & 3); dma(k1 + 2, (k1 + 2) & 3); }
        __builtin_amdgcn_sched_barrier(0);

        const u16* bZ0 = smem + (k0 & 3) * 4096;
        const u16* bW0 = smem + 16384 + (k0 & 3) * 4096;
        const u16* bZ1 = smem + (k1 & 3) * 4096;
        const u16* bW1 = smem + 16384 + (k1 & 3) * 4096;

        bf8 a0[4], g0[4], a1[4], g1[4];
        #pragma unroll
        for (int mi = 0; mi < 4; ++mi)
            a0[mi] = *(const bf8*)(bW0 + (wo + mi * 16 + lr) * 32 + rchunk);
        #pragma unroll
        for (int ni = 0; ni < 4; ++ni)
            g0[ni] = *(const bf8*)(bZ0 + (wt + ni * 16 + lr) * 32 + rchunk);
        __builtin_amdgcn_sched_barrier(0);
        #pragma unroll
        for (int mi = 0; mi < 4; ++mi)
            a1[mi] = *(const bf8*)(bW1 + (wo + mi * 16 + lr) * 32 + rchunk);
        #pragma unroll
        for (int ni = 0; ni < 4; ++ni)
            g1[ni] = *(const bf8*)(bZ1 + (wt + ni * 16 + lr) * 32 + rchunk);

        asm volatile("s_waitcnt lgkmcnt(8)" ::: "memory");
        __builtin_amdgcn_sched_barrier(0);
        __builtin_amdgcn_s_setprio(1);
        #pragma unroll
        for (int mi = 0; mi < 4; ++mi)
            #pragma unroll
            for (int ni = 0; ni < 4; ++ni)
                acc[mi][ni] = __builtin_amdgcn_mfma_f32_16x16x32_bf16(
                    a0[mi], g0[ni], acc[mi][ni], 0, 0, 0);
        __builtin_amdgcn_s_setprio(0);

        asm volatile("s_waitcnt lgkmcnt(0)" ::: "memory");
        __builtin_amdgcn_sched_barrier(0);
        __builtin_amdgcn_s_setprio(1);
        #pragma unroll
        for (int mi = 0; mi < 4; ++mi)
            #pragma unroll
            for (int ni = 0; ni < 4; ++ni)
                acc[mi][ni] = __builtin_amdgcn_mfma_f32_16x16x32_bf16(
                    a1[mi], g1[ni], acc[mi][ni], 0, 0, 0);
        __builtin_amdgcn_s_setprio(0);
    }

    float biasv[4][4];
    #pragma unroll
    for (int mi = 0; mi < 4; ++mi) {
        float4 bb = *(const float4*)(bA + o0 + wo + mi * 16 + quad * 4);
        biasv[mi][0] = bb.x; biasv[mi][1] = bb.y; biasv[mi][2] = bb.z; biasv[mi][3] = bb.w;
    }

    // ---- part A: barrier-free rolling xres prefetch + out writes ----------
    float xr0[16], xr1[16];      // two ni-groups in flight (16 dwords each)
    ushort4 pkv[4][4];           // packed bf16 results for part B
    auto issue = [&](int ni, float* dst) {
        #pragma unroll
        for (int mi = 0; mi < 4; ++mi)
            #pragma unroll
            for (int r = 0; r < 4; ++r) {
                int o = o0 + wo + mi * 16 + quad * 4 + r;
                dst[mi * 4 + r] =
                    xres[((size_t)b * Cn + o) * Tn + t0 + wt + ni * 16 + lr];
            }
    };
    issue(0, xr0);
    #pragma unroll
    for (int ni = 0; ni < 4; ++ni) {
        float* cur = (ni & 1) ? xr1 : xr0;
        float* nxt = (ni & 1) ? xr0 : xr1;
        if (ni + 1 < 4) issue(ni + 1, nxt);
        #pragma unroll
        for (int mi = 0; mi < 4; ++mi) {
            ushort4 pk;
            #pragma unroll
            for (int r = 0; r < 4; ++r) {
                int o = o0 + wo + mi * 16 + quad * 4 + r;
                size_t idx = ((size_t)b * Cn + o) * Tn + t0 + wt + ni * 16 + lr;
                float v = acc[mi][ni][r] + biasv[mi][r] + cur[mi * 4 + r];
                out[idx] = v;
                ((u16*)&pk)[r] = f2bf(lrelu(v));
            }
            pkv[ni][mi] = pk;
        }
    }

    // ---- part B: coalesced xT transpose via per-wave LDS strips -----------
    if (writeXT) {
        u16* strip = smem + wv * 1152;     // 16t x 64o, padded rows (72 u16)
        u16* xTb2 = xTn + (size_t)b * Tn * Cn;
        #pragma unroll
        for (int ni = 0; ni < 4; ++ni) {
            __syncthreads();   // staging/strip LDS free of readers
            #pragma unroll
            for (int mi = 0; mi < 4; ++mi)
                *(ushort4*)(strip + lr * 72 + mi * 16 + quad * 4) = pkv[ni][mi];
            __syncthreads();   // strip writes visible
            #pragma unroll
            for (int it = 0; it < 2; ++it) {
                int tt = (lane >> 3) + it * 8;
                uint4 vv = *(const uint4*)(strip + tt * 72 + (lane & 7) * 8);
                *(uint4*)(xTb2 + (size_t)(t0 + wt + ni * 16 + tt) * Cn
                          + o0 + wo + (lane & 7) * 8) = vv;
            }
        }
    }
}

extern "C" void kernel_launch(void* const* d_in, const int* in_sizes, int n_in,
                              void* d_out, int out_size, void* d_ws, size_t ws_size,
                              hipStream_t stream)
{
    const float* x  = (const float*)d_in[0];
    const float* d  = (const float*)d_in[1];
    const float* WC = (const float*)d_in[2];
    const float* bC = (const float*)d_in[3];
    const float* WP = (const float*)d_in[4];
    const float* bP = (const float*)d_in[5];
    const float* WF = (const float*)d_in[6];
    const float* bF = (const float*)d_in[7];
    const float* WA = (const float*)d_in[8];
    const float* bA = (const float*)d_in[9];
    float* out = (float*)d_out;

    char* ws = (char*)d_ws;
    u16*   xT   = (u16*)(ws);                                   // 32 MiB
    u16*   zT   = (u16*)(ws + (size_t)Bn * Tn * Cn * 2);        // 32 MiB
    u16*   Wcat = (u16*)(ws + (size_t)2 * Bn * Tn * Cn * 2);    // 1.125 MiB
    u16*   WAp  = Wcat + (size_t)NL * Cn * Kc;                  // 1.125 MiB
    float* bSum = (float*)(WAp + (size_t)NL * Cn * Kc);         // 3 KiB
    u16*   zrow = (u16*)(bSum + NL * Cn);                       // 512 B zero row

    k_wprep<<<dim3(1024), dim3(256), 0, stream>>>(WC, WP, WF, WA, bC, bP, bF,
                                                  Wcat, WAp, bSum, zrow);

    dim3 gP(Tn / 64, Cn / 64, Bn);      // prep: 128 x 4 x 8
    dim3 gG(128, 1, Bn);                // gemms: flat 128 tiles x 8 batches
    dim3 blk(256);

    k_prep<<<gP, blk, 0, stream>>>(x, xT);   // layer-0 input only

    const float dils[NL] = {1.f, 2.f, 4.f};
    const float* xcur = x;
    for (int i = 0; i < NL; ++i) {
        k_gemm1<<<gG, blk, 0, stream>>>(xT, d,
                                        Wcat + (size_t)i * Cn * Kc,
                                        bSum + (size_t)i * Cn,
                                        dils[i], zT, zrow);
        k_gemm2<<<gG, blk, 0, stream>>>(zT,
                                        WAp + (size_t)i * Cn * Kc,
                                        bA + (size_t)i * Cn,
                                        xcur, out, xT, (i < NL - 1) ? 1 : 0,
                                        zrow);
        xcur = out;   // residual read-then-write same element: in-place safe
    }
}